// Round 1
// baseline (1598.560 us; speedup 1.0000x reference)
//
#include <hip/hip_runtime.h>
#include <cstdint>

// Problem dims
#define N_IMG 64
#define IC1   128
#define HWI   56
#define OCN   256
#define HWO   28
#define PX_PER_IMG (HWO*HWO)          // 784
#define NPX  (N_IMG*PX_PER_IMG)       // 50176

typedef float  f32x4_t  __attribute__((ext_vector_type(4)));
typedef __bf16 bf16x8_t __attribute__((ext_vector_type(8)));

__device__ __forceinline__ float fsign(float v) {
    return v > 0.f ? 1.f : (v < 0.f ? -1.f : 0.f);
}
__device__ __forceinline__ unsigned short bsign_bits(float v) {
    // bf16 bit patterns for +1 / -1 / 0
    return v > 0.f ? (unsigned short)0x3F80 : (v < 0.f ? (unsigned short)0xBF80 : (unsigned short)0);
}

// ---------------------------------------------------------------------------
// Weight pre-transform: apply sign(), re-layout for the conv kernels.
//  W1t : [ic][kidx][oc] fp32  (128*9*256)
//  Wsct: [ic][oc]       fp32  (128*256)
//  W2t : [kidx][oc][ic] bf16  (9*256*256)
// ---------------------------------------------------------------------------
__global__ void transform_weights(const float* __restrict__ w1,
                                  const float* __restrict__ w2,
                                  const float* __restrict__ wsc,
                                  float* __restrict__ W1t,
                                  float* __restrict__ Wsct,
                                  unsigned short* __restrict__ W2t) {
    int idx = blockIdx.x * 256 + threadIdx.x;
    if (idx < 128*9*256) {                       // W1t
        int oc = idx & 255; int rest = idx >> 8;
        int kidx = rest % 9; int ic = rest / 9;
        W1t[idx] = fsign(w1[(oc*IC1 + ic)*9 + kidx]);
    }
    idx -= 128*9*256;
    if (idx >= 0 && idx < 128*256) {             // Wsct
        int oc = idx & 255; int ic = idx >> 8;
        Wsct[idx] = fsign(wsc[oc*IC1 + ic]);
    }
    idx -= 128*256;
    if (idx >= 0 && idx < 9*256*256) {           // W2t
        int ic = idx & 255; int rest = idx >> 8;
        int oc = rest & 255; int kidx = rest >> 8;
        W2t[idx] = bsign_bits(w2[(oc*OCN + ic)*9 + kidx]);
    }
}

// ---------------------------------------------------------------------------
// convA: conv1 (3x3 s2 p1, binary weights) + sign  -> S  [n][oy][ox][oc] bf16 bits
//        shortcut (1x1 s2, binary weights)         -> I  [n][oy][ox][oc] fp32
// fp32 vector math (sign() correctness requires fp32-faithful accumulation).
// Block: 256 thr = 64 oc-lanes x 4 row-waves. Tile: 4 out rows x 28 cols x 64 oc.
// Each thread: 1 oc, one full 28-px output row (acc[28] + accid[28]).
// Whole wave reads the same Xs row -> LDS broadcast.
// ---------------------------------------------------------------------------
__global__ __launch_bounds__(256, 2) void convA(const float* __restrict__ x,
                                                const float* __restrict__ W1t,
                                                const float* __restrict__ Wsct,
                                                unsigned short* __restrict__ S,
                                                float* __restrict__ I) {
    __shared__ float Xs[16*9*60];   // [ic16][row9][col60]  (58 used, stride 60 -> 240B rows, 16B aligned)
    __shared__ float Ws[16*9*64];   // [ic16][kidx9][oc64]
    __shared__ float Wscs[16*64];   // [ic16][oc64]

    const int t      = threadIdx.x;
    const int oc0    = blockIdx.x * 64;   // 4 tiles
    const int ytile  = blockIdx.y;        // 7 tiles of 4 rows
    const int n      = blockIdx.z;        // 64
    const int tid_oc = t & 63;
    const int tid_r  = t >> 6;            // 0..3 (== wave id)
    const int oy     = ytile*4 + tid_r;

    float acc[28], accid[28];
    #pragma unroll
    for (int p = 0; p < 28; ++p) { acc[p] = 0.f; accid[p] = 0.f; }

    for (int ic0 = 0; ic0 < IC1; ic0 += 16) {
        __syncthreads();
        // ---- stage X tile: 16 ic x 9 rows x 58 cols (col = ix+1, zero-padded)
        for (int li = t; li < 16*9*58; li += 256) {
            int col = li % 58;
            int ri  = li / 58;            // 0..143
            int r   = ri % 9;
            int ic  = ri / 9;
            int iy  = ytile*8 - 1 + r;
            int ix  = col - 1;
            float v = 0.f;
            if (iy >= 0 && iy < HWI && ix >= 0 && ix < HWI)
                v = x[((n*IC1 + ic0 + ic)*HWI + iy)*HWI + ix];
            Xs[(ic*9 + r)*60 + col] = v;
        }
        // ---- stage conv1 weights (already signed fp32): [ic][kidx][oc64]
        for (int li = t; li < 16*9*64; li += 256) {
            int oc = li & 63; int ri = li >> 6;
            int kidx = ri % 9; int ic = ri / 9;
            Ws[li] = W1t[((ic0 + ic)*9 + kidx)*OCN + oc0 + oc];
        }
        // ---- stage shortcut weights
        for (int li = t; li < 16*64; li += 256) {
            int oc = li & 63; int ic = li >> 6;
            Wscs[li] = Wsct[(ic0 + ic)*OCN + oc0 + oc];
        }
        __syncthreads();

        for (int ic = 0; ic < 16; ++ic) {
            #pragma unroll
            for (int ky = 0; ky < 3; ++ky) {
                // load full input row (60 floats, broadcast across wave)
                float xv[60];
                const float4* rp = (const float4*)&Xs[(ic*9 + 2*tid_r + ky)*60];
                #pragma unroll
                for (int i = 0; i < 15; ++i) *(float4*)&xv[i*4] = rp[i];
                #pragma unroll
                for (int kx = 0; kx < 3; ++kx) {
                    float w = Ws[(ic*9 + ky*3 + kx)*64 + tid_oc];
                    #pragma unroll
                    for (int p = 0; p < 28; ++p)
                        acc[p] = __builtin_fmaf(xv[2*p + kx], w, acc[p]);
                }
                if (ky == 1) {  // shortcut taps x[2oy][2ox] = row (2*tid_r+1), col (2p+1)
                    float wsc = Wscs[ic*64 + tid_oc];
                    #pragma unroll
                    for (int p = 0; p < 28; ++p)
                        accid[p] = __builtin_fmaf(xv[2*p + 1], wsc, accid[p]);
                }
            }
        }
    }

    // ---- write S (sign as bf16 bits) and identity (fp32), channels-last
    #pragma unroll
    for (int p = 0; p < 28; ++p) {
        int sidx = ((n*HWO + oy)*HWO + p)*OCN + oc0 + tid_oc;
        S[sidx] = bsign_bits(acc[p]);
        I[sidx] = accid[p];
    }
}

// ---------------------------------------------------------------------------
// convB: conv2 (3x3 s1 p1, binary weights, binary inputs) + identity + sign.
// GEMM per (ky,kx) shift, K = ic (channels-last S => contiguous bf16x8 frags).
// Exact: products are +-1 bf16, fp32 accumulation of small integers.
// Block: 256 thr (4 waves). Tile: 256 oc x 64 px. Wave = 64 oc x 64 px, acc 4x4.
// LDS rows padded to 40 halfwords (80B) -> conflict-free-ish b128 reads.
// ---------------------------------------------------------------------------
#define SPAD 40
__global__ __launch_bounds__(256, 2) void convB(const unsigned short* __restrict__ S,
                                                const unsigned short* __restrict__ W2t,
                                                const float* __restrict__ I,
                                                float* __restrict__ out) {
    __shared__ unsigned short As[256*SPAD];  // [oc256][ic32 padded]
    __shared__ unsigned short Bs[64*SPAD];   // [px64][ic32 padded]

    const int t    = threadIdx.x;
    const int lane = t & 63;
    const int wave = t >> 6;
    const int px0  = blockIdx.x * 64;        // 784 blocks

    f32x4_t acc[4][4];
    #pragma unroll
    for (int mi = 0; mi < 4; ++mi)
        #pragma unroll
        for (int ni = 0; ni < 4; ++ni)
            acc[mi][ni] = (f32x4_t)0.f;

    // this thread's Bs staging coordinates (fixed over the k-loop)
    const int b_px  = t >> 2;                // 0..63
    const int b_icg = t & 3;                 // 0..3 (8 ic each)
    const int pxg   = px0 + b_px;
    const int nb    = pxg / PX_PER_IMG;
    const int prb   = pxg % PX_PER_IMG;
    const int oyb   = prb / HWO;
    const int oxb   = prb % HWO;

    for (int ic0 = 0; ic0 < OCN; ic0 += 32) {
        for (int kidx = 0; kidx < 9; ++kidx) {
            const int ky = kidx / 3, kx = kidx % 3;
            __syncthreads();
            // ---- stage A: 256 oc x 32 ic  (1024 x 16B)
            #pragma unroll
            for (int i = 0; i < 4; ++i) {
                int u  = t + 256*i;
                int oc = u >> 2, icg = u & 3;
                uint4 v = *(const uint4*)&W2t[(kidx*OCN + oc)*OCN + ic0 + icg*8];
                *(uint4*)&As[oc*SPAD + icg*8] = v;
            }
            // ---- stage B: 64 px x 32 ic (shifted, zero-padded)
            {
                int sy = oyb + ky - 1, sx = oxb + kx - 1;
                uint4 v = make_uint4(0u, 0u, 0u, 0u);
                if (sy >= 0 && sy < HWO && sx >= 0 && sx < HWO)
                    v = *(const uint4*)&S[((nb*HWO + sy)*HWO + sx)*OCN + ic0 + b_icg*8];
                *(uint4*)&Bs[b_px*SPAD + b_icg*8] = v;
            }
            __syncthreads();
            // ---- 16 MFMAs per wave (64oc x 64px x K32)
            bf16x8_t a[4], b[4];
            #pragma unroll
            for (int mi = 0; mi < 4; ++mi) {
                int oc = wave*64 + mi*16 + (lane & 15);
                a[mi] = __builtin_bit_cast(bf16x8_t, *(const uint4*)&As[oc*SPAD + (lane >> 4)*8]);
            }
            #pragma unroll
            for (int ni = 0; ni < 4; ++ni) {
                int px = ni*16 + (lane & 15);
                b[ni] = __builtin_bit_cast(bf16x8_t, *(const uint4*)&Bs[px*SPAD + (lane >> 4)*8]);
            }
            #pragma unroll
            for (int mi = 0; mi < 4; ++mi)
                #pragma unroll
                for (int ni = 0; ni < 4; ++ni)
                    acc[mi][ni] = __builtin_amdgcn_mfma_f32_16x16x32_bf16(a[mi], b[ni], acc[mi][ni], 0, 0, 0);
        }
    }

    // ---- epilogue: + identity, sign, scatter to NCHW fp32
    #pragma unroll
    for (int ni = 0; ni < 4; ++ni) {
        int px = px0 + ni*16 + (lane & 15);
        int n  = px / PX_PER_IMG;
        int pr = px % PX_PER_IMG;
        int oy = pr / HWO, ox = pr % HWO;
        #pragma unroll
        for (int mi = 0; mi < 4; ++mi) {
            int oc = wave*64 + mi*16 + (lane >> 4)*4;
            f32x4_t idv = *(const f32x4_t*)&I[(size_t)px*OCN + oc];
            #pragma unroll
            for (int r = 0; r < 4; ++r) {
                float v = acc[mi][ni][r] + idv[r];
                out[((size_t)(n*OCN + oc + r)*HWO + oy)*HWO + ox] = fsign(v);
            }
        }
    }
}

// ---------------------------------------------------------------------------
// Workspace layout (bytes, all 256-aligned):
//  S    : 12,845,056 * 2 = 25,690,112
//  I    : 12,845,056 * 4 = 51,380,224
//  W1t  : 294,912 * 4    =  1,179,648
//  Wsct : 32,768 * 4     =    131,072
//  W2t  : 589,824 * 2    =  1,179,648
//  total ~ 79.6 MB
// ---------------------------------------------------------------------------
extern "C" void kernel_launch(void* const* d_in, const int* in_sizes, int n_in,
                              void* d_out, int out_size, void* d_ws, size_t ws_size,
                              hipStream_t stream) {
    (void)in_sizes; (void)n_in; (void)out_size; (void)ws_size;
    const float* x   = (const float*)d_in[0];
    const float* w1  = (const float*)d_in[1];
    const float* w2  = (const float*)d_in[2];
    const float* wsc = (const float*)d_in[3];
    float* out = (float*)d_out;

    char* ws = (char*)d_ws;
    unsigned short* S    = (unsigned short*)(ws);
    float*          I    = (float*)(ws + 25690112u);
    float*          W1t  = (float*)(ws + 25690112u + 51380224u);
    float*          Wsct = (float*)(ws + 25690112u + 51380224u + 1179648u);
    unsigned short* W2t  = (unsigned short*)(ws + 25690112u + 51380224u + 1179648u + 131072u);

    hipLaunchKernelGGL(transform_weights, dim3(3584), dim3(256), 0, stream,
                       w1, w2, wsc, W1t, Wsct, W2t);
    hipLaunchKernelGGL(convA, dim3(4, 7, 64), dim3(256), 0, stream,
                       x, W1t, Wsct, S, I);
    hipLaunchKernelGGL(convB, dim3(784), dim3(256), 0, stream,
                       S, W2t, I, out);
}

// Round 2
// 1355.872 us; speedup vs baseline: 1.1790x; 1.1790x over previous
//
#include <hip/hip_runtime.h>
#include <cstdint>

// Problem dims
#define N_IMG 64
#define IC1   128
#define HWI   56
#define OCN   256
#define HWO   28
#define PX_PER_IMG (HWO*HWO)          // 784
#define NPX  (N_IMG*PX_PER_IMG)       // 50176

typedef float  f32x4_t  __attribute__((ext_vector_type(4)));
typedef __bf16 bf16x8_t __attribute__((ext_vector_type(8)));

__device__ __forceinline__ float fsign(float v) {
    return v > 0.f ? 1.f : (v < 0.f ? -1.f : 0.f);
}
__device__ __forceinline__ unsigned short bsign_bits(float v) {
    return v > 0.f ? (unsigned short)0x3F80 : (v < 0.f ? (unsigned short)0xBF80 : (unsigned short)0);
}

// ---------------------------------------------------------------------------
// Weight pre-transform.
//  W1t : [ocb4][ic128][kidx9][oc64] fp32  -- linear per (ocb, ic-chunk) slice
//  Wsct: [ocb4][ic128][oc64]       fp32
//  W2t : [kidx][oc][ic]            bf16 bits
// ---------------------------------------------------------------------------
__global__ void transform_weights(const float* __restrict__ w1,
                                  const float* __restrict__ w2,
                                  const float* __restrict__ wsc,
                                  float* __restrict__ W1t,
                                  float* __restrict__ Wsct,
                                  unsigned short* __restrict__ W2t) {
    int idx = blockIdx.x * 256 + threadIdx.x;
    if (idx < 128*9*256) {                       // W1t
        int oc = idx & 255; int rest = idx >> 8;
        int kidx = rest % 9; int ic = rest / 9;
        float v = fsign(w1[(oc*IC1 + ic)*9 + kidx]);
        W1t[(((oc >> 6)*IC1 + ic)*9 + kidx)*64 + (oc & 63)] = v;
    }
    idx -= 128*9*256;
    if (idx >= 0 && idx < 128*256) {             // Wsct
        int oc = idx & 255; int ic = idx >> 8;
        Wsct[((oc >> 6)*IC1 + ic)*64 + (oc & 63)] = fsign(wsc[oc*IC1 + ic]);
    }
    idx -= 128*256;
    if (idx >= 0 && idx < 9*256*256) {           // W2t
        int ic = idx & 255; int rest = idx >> 8;
        int oc = rest & 255; int kidx = rest >> 8;
        W2t[idx] = bsign_bits(w2[(oc*OCN + ic)*9 + kidx]);
    }
}

// ---------------------------------------------------------------------------
// convA: conv1 (3x3 s2 p1) + sign -> S [n][oy][ox][oc] bf16-bits
//        shortcut (1x1 s2)        -> I [n][oy][ox][oc] fp32
// fp32 VALU. Block: 256 thr = 64 oc x 4 row-waves. Tile: 4 rows x 28 x 64 oc.
// Xs in LDS (18.4KB, broadcast reads); weights straight from global (L2-hot).
// x-row consumed in 2 chunks (36/28 floats) to keep live regs < 128: no spill.
// ---------------------------------------------------------------------------
__global__ __launch_bounds__(256, 4) void convA(const float* __restrict__ x,
                                                const float* __restrict__ W1t,
                                                const float* __restrict__ Wsct,
                                                unsigned short* __restrict__ S,
                                                float* __restrict__ I) {
    __shared__ float Xs[8*9*64];   // [ic8][row9][col64]; col = ix+1

    const int t      = threadIdx.x;
    const int ocb    = blockIdx.x;        // 4
    const int oc0    = ocb * 64;
    const int ytile  = blockIdx.y;        // 7
    const int n      = blockIdx.z;        // 64
    const int tid_oc = t & 63;
    const int tid_r  = t >> 6;            // 0..3 (wave id)
    const int oy     = ytile*4 + tid_r;

    float acc[28], accid[28];
    #pragma unroll
    for (int p = 0; p < 28; ++p) { acc[p] = 0.f; accid[p] = 0.f; }

    const int s_ic  = t >> 6;             // staging role: base ic
    const int s_col = t & 63;
    const int s_ix  = s_col - 1;

    for (int ic0 = 0; ic0 < IC1; ic0 += 8) {
        __syncthreads();
        // ---- stage Xs: 8 ic x 9 rows x 64 cols, coalesced, no idiv
        #pragma unroll
        for (int r = 0; r < 9; ++r) {
            int iy = ytile*8 - 1 + r;
            #pragma unroll
            for (int i = 0; i < 2; ++i) {
                int ic = s_ic + i*4;
                float v = 0.f;
                if (iy >= 0 && iy < HWI && (unsigned)s_ix < (unsigned)HWI)
                    v = x[((n*IC1 + ic0 + ic)*HWI + iy)*HWI + s_ix];
                Xs[(ic*9 + r)*64 + s_col] = v;
            }
        }
        __syncthreads();

        const float* __restrict__ wchunk   = W1t  + ((size_t)(ocb*IC1 + ic0)*9)*64 + tid_oc;
        const float* __restrict__ wscchunk = Wsct + (size_t)(ocb*IC1 + ic0)*64 + tid_oc;

        for (int ic = 0; ic < 8; ++ic) {
            float w[9];
            #pragma unroll
            for (int k = 0; k < 9; ++k) w[k] = wchunk[(ic*9 + k)*64];
            const float wsc = wscchunk[ic*64];
            const float* xb = &Xs[(ic*9 + 2*tid_r)*64];

            #pragma unroll
            for (int ky = 0; ky < 3; ++ky) {
                const float* rp = xb + ky*64;
                {   // chunk 0: outputs p 0..15, cols 0..35
                    float xv[36];
                    #pragma unroll
                    for (int i2 = 0; i2 < 9; ++i2)
                        *(float4*)&xv[i2*4] = *(const float4*)&rp[i2*4];
                    #pragma unroll
                    for (int kx = 0; kx < 3; ++kx) {
                        float wv = w[ky*3 + kx];
                        #pragma unroll
                        for (int p = 0; p < 16; ++p)
                            acc[p] = __builtin_fmaf(xv[2*p + kx], wv, acc[p]);
                    }
                    if (ky == 1) {
                        #pragma unroll
                        for (int p = 0; p < 16; ++p)
                            accid[p] = __builtin_fmaf(xv[2*p + 1], wsc, accid[p]);
                    }
                }
                {   // chunk 1: outputs p 16..27, cols 32..59
                    float yv[28];
                    #pragma unroll
                    for (int i2 = 0; i2 < 7; ++i2)
                        *(float4*)&yv[i2*4] = *(const float4*)&rp[32 + i2*4];
                    #pragma unroll
                    for (int kx = 0; kx < 3; ++kx) {
                        float wv = w[ky*3 + kx];
                        #pragma unroll
                        for (int p = 16; p < 28; ++p)
                            acc[p] = __builtin_fmaf(yv[2*p + kx - 32], wv, acc[p]);
                    }
                    if (ky == 1) {
                        #pragma unroll
                        for (int p = 16; p < 28; ++p)
                            accid[p] = __builtin_fmaf(yv[2*p + 1 - 32], wsc, accid[p]);
                    }
                }
            }
        }
    }

    // ---- write S (bf16-bit sign) and identity (fp32), channels-last
    #pragma unroll
    for (int p = 0; p < 28; ++p) {
        int sidx = ((n*HWO + oy)*HWO + p)*OCN + oc0 + tid_oc;
        S[sidx] = bsign_bits(acc[p]);
        I[sidx] = accid[p];
    }
}

// ---------------------------------------------------------------------------
// convB: conv2 (3x3 s1 p1, binary x binary) via MFMA + identity + sign.
// Unchanged from round 1 (measured ~130us incl. transform).
// ---------------------------------------------------------------------------
#define SPAD 40
__global__ __launch_bounds__(256, 2) void convB(const unsigned short* __restrict__ S,
                                                const unsigned short* __restrict__ W2t,
                                                const float* __restrict__ I,
                                                float* __restrict__ out) {
    __shared__ unsigned short As[256*SPAD];  // [oc256][ic32 padded]
    __shared__ unsigned short Bs[64*SPAD];   // [px64][ic32 padded]

    const int t    = threadIdx.x;
    const int lane = t & 63;
    const int wave = t >> 6;
    const int px0  = blockIdx.x * 64;        // 784 blocks

    f32x4_t acc[4][4];
    #pragma unroll
    for (int mi = 0; mi < 4; ++mi)
        #pragma unroll
        for (int ni = 0; ni < 4; ++ni)
            acc[mi][ni] = (f32x4_t)0.f;

    const int b_px  = t >> 2;
    const int b_icg = t & 3;
    const int pxg   = px0 + b_px;
    const int nb    = pxg / PX_PER_IMG;
    const int prb   = pxg % PX_PER_IMG;
    const int oyb   = prb / HWO;
    const int oxb   = prb % HWO;

    for (int ic0 = 0; ic0 < OCN; ic0 += 32) {
        for (int kidx = 0; kidx < 9; ++kidx) {
            const int ky = kidx / 3, kx = kidx % 3;
            __syncthreads();
            #pragma unroll
            for (int i = 0; i < 4; ++i) {
                int u  = t + 256*i;
                int oc = u >> 2, icg = u & 3;
                uint4 v = *(const uint4*)&W2t[(kidx*OCN + oc)*OCN + ic0 + icg*8];
                *(uint4*)&As[oc*SPAD + icg*8] = v;
            }
            {
                int sy = oyb + ky - 1, sx = oxb + kx - 1;
                uint4 v = make_uint4(0u, 0u, 0u, 0u);
                if (sy >= 0 && sy < HWO && sx >= 0 && sx < HWO)
                    v = *(const uint4*)&S[((nb*HWO + sy)*HWO + sx)*OCN + ic0 + b_icg*8];
                *(uint4*)&Bs[b_px*SPAD + b_icg*8] = v;
            }
            __syncthreads();
            bf16x8_t a[4], b[4];
            #pragma unroll
            for (int mi = 0; mi < 4; ++mi) {
                int oc = wave*64 + mi*16 + (lane & 15);
                a[mi] = __builtin_bit_cast(bf16x8_t, *(const uint4*)&As[oc*SPAD + (lane >> 4)*8]);
            }
            #pragma unroll
            for (int ni = 0; ni < 4; ++ni) {
                int px = ni*16 + (lane & 15);
                b[ni] = __builtin_bit_cast(bf16x8_t, *(const uint4*)&Bs[px*SPAD + (lane >> 4)*8]);
            }
            #pragma unroll
            for (int mi = 0; mi < 4; ++mi)
                #pragma unroll
                for (int ni = 0; ni < 4; ++ni)
                    acc[mi][ni] = __builtin_amdgcn_mfma_f32_16x16x32_bf16(a[mi], b[ni], acc[mi][ni], 0, 0, 0);
        }
    }

    #pragma unroll
    for (int ni = 0; ni < 4; ++ni) {
        int px = px0 + ni*16 + (lane & 15);
        int n  = px / PX_PER_IMG;
        int pr = px % PX_PER_IMG;
        int oy = pr / HWO, ox = pr % HWO;
        #pragma unroll
        for (int mi = 0; mi < 4; ++mi) {
            int oc = wave*64 + mi*16 + (lane >> 4)*4;
            f32x4_t idv = *(const f32x4_t*)&I[(size_t)px*OCN + oc];
            #pragma unroll
            for (int r = 0; r < 4; ++r) {
                float v = acc[mi][ni][r] + idv[r];
                out[((size_t)(n*OCN + oc + r)*HWO + oy)*HWO + ox] = fsign(v);
            }
        }
    }
}

// ---------------------------------------------------------------------------
// Workspace layout (bytes):
//  S    : 25,690,112   I: 51,380,224   W1t: 1,179,648   Wsct: 131,072
//  W2t  : 1,179,648    total ~ 79.6 MB
// ---------------------------------------------------------------------------
extern "C" void kernel_launch(void* const* d_in, const int* in_sizes, int n_in,
                              void* d_out, int out_size, void* d_ws, size_t ws_size,
                              hipStream_t stream) {
    (void)in_sizes; (void)n_in; (void)out_size; (void)ws_size;
    const float* x   = (const float*)d_in[0];
    const float* w1  = (const float*)d_in[1];
    const float* w2  = (const float*)d_in[2];
    const float* wsc = (const float*)d_in[3];
    float* out = (float*)d_out;

    char* ws = (char*)d_ws;
    unsigned short* S    = (unsigned short*)(ws);
    float*          I    = (float*)(ws + 25690112u);
    float*          W1t  = (float*)(ws + 25690112u + 51380224u);
    float*          Wsct = (float*)(ws + 25690112u + 51380224u + 1179648u);
    unsigned short* W2t  = (unsigned short*)(ws + 25690112u + 51380224u + 1179648u + 131072u);

    hipLaunchKernelGGL(transform_weights, dim3(3584), dim3(256), 0, stream,
                       w1, w2, wsc, W1t, Wsct, W2t);
    hipLaunchKernelGGL(convA, dim3(4, 7, 64), dim3(256), 0, stream,
                       x, W1t, Wsct, S, I);
    hipLaunchKernelGGL(convB, dim3(784), dim3(256), 0, stream,
                       S, W2t, I, out);
}

// Round 5
// 895.866 us; speedup vs baseline: 1.7844x; 1.5135x over previous
//
#include <hip/hip_runtime.h>
#include <cstdint>

// Problem dims
#define N_IMG 64
#define IC1   128
#define HWI   56
#define OCN   256
#define HWO   28
#define PX_PER_IMG (HWO*HWO)          // 784

typedef float  f32x4_t  __attribute__((ext_vector_type(4)));
typedef __bf16 bf16x8_t __attribute__((ext_vector_type(8)));

__device__ __forceinline__ float fsign(float v) {
    return v > 0.f ? 1.f : (v < 0.f ? -1.f : 0.f);
}
__device__ __forceinline__ unsigned short bsign_bits(float v) {
    return v > 0.f ? (unsigned short)0x3F80 : (v < 0.f ? (unsigned short)0xBF80 : (unsigned short)0);
}

// ---------------------------------------------------------------------------
// Weight pre-transform (byte-identical to validated round 2).
//  W1t : [ocb4][ic128][kidx9][oc64] fp32
//  Wsct: [ocb4][ic128][oc64]        fp32
//  W2t : [kidx9][oc256][ic256]      bf16 bits
// ---------------------------------------------------------------------------
__global__ void transform_weights(const float* __restrict__ w1,
                                  const float* __restrict__ w2,
                                  const float* __restrict__ wsc,
                                  float* __restrict__ W1t,
                                  float* __restrict__ Wsct,
                                  unsigned short* __restrict__ W2t) {
    int idx = blockIdx.x * 256 + threadIdx.x;
    if (idx < 128*9*256) {                       // W1t
        int oc = idx & 255; int rest = idx >> 8;
        int kidx = rest % 9; int ic = rest / 9;
        float v = fsign(w1[(oc*IC1 + ic)*9 + kidx]);
        W1t[(((oc >> 6)*IC1 + ic)*9 + kidx)*64 + (oc & 63)] = v;
    }
    idx -= 128*9*256;
    if (idx >= 0 && idx < 128*256) {             // Wsct
        int oc = idx & 255; int ic = idx >> 8;
        Wsct[((oc >> 6)*IC1 + ic)*64 + (oc & 63)] = fsign(wsc[oc*IC1 + ic]);
    }
    idx -= 128*256;
    if (idx >= 0 && idx < 9*256*256) {           // W2t
        int ic = idx & 255; int rest = idx >> 8;
        int oc = rest & 255; int kidx = rest >> 8;
        W2t[idx] = bsign_bits(w2[(oc*OCN + ic)*9 + kidx]);
    }
}

// ---------------------------------------------------------------------------
// convA: conv1 (3x3 s2 p1) + sign -> S; shortcut (1x1 s2) -> I.
// EXACT round-1/2 fp32 accumulation order per output (ic 0..127 ascending;
// per ic: ky 0..2, kx 0..2; shortcut fma at ky==1) -- the order that
// validated with absmax 0.0 twice. Restructured for zero spill:
//   block 256 thr = 64 oc x {2 out-rows x 2 half-rows}; 14 px per thread.
//   live set ~90 regs (acc14+accid14+xv32+w10+addr) < 128.
// LDS: 10.2KB x-slab (8 ic x 5 rows x 64 cols), wave-broadcast reads.
// Weights read from global (L2-hot, coalesced b32).
// ---------------------------------------------------------------------------
__global__ __launch_bounds__(256, 2) void convA(const float* __restrict__ x,
                                                const float* __restrict__ W1t,
                                                const float* __restrict__ Wsct,
                                                unsigned short* __restrict__ S,
                                                float* __restrict__ I) {
    __shared__ float Xs[8*5*64];   // [ic8][row5][col64]; col = ix+1

    const int t      = threadIdx.x;
    const int ocb    = blockIdx.x;        // 4
    const int oc0    = ocb * 64;
    const int ytile  = blockIdx.y;        // 14 (2 out rows each)
    const int n      = blockIdx.z;        // 64
    const int tid_oc = t & 63;
    const int u      = t >> 6;            // 0..3
    const int tid_r  = u >> 1;            // 0..1 : out row within tile
    const int h      = u & 1;             // 0..1 : half-row (14 px)

    float acc[14], accid[14];
    #pragma unroll
    for (int p = 0; p < 14; ++p) { acc[p] = 0.f; accid[p] = 0.f; }

    const int s_col = t & 63;
    const int s_icw = (t >> 6) * 2;       // staging: 2 ic per thread-group
    const int s_ix  = s_col - 1;

    for (int ic0 = 0; ic0 < IC1; ic0 += 8) {
        __syncthreads();
        // ---- stage Xs: 8 ic x 5 rows x 64 cols, coalesced, guarded zero-pad
        #pragma unroll
        for (int r = 0; r < 5; ++r) {
            int iy = 4*ytile - 1 + r;
            #pragma unroll
            for (int j = 0; j < 2; ++j) {
                int ic = s_icw + j;
                float v = 0.f;
                if ((unsigned)iy < (unsigned)HWI && (unsigned)s_ix < (unsigned)HWI)
                    v = x[((size_t)(n*IC1 + ic0 + ic)*HWI + iy)*HWI + s_ix];
                Xs[(ic*5 + r)*64 + s_col] = v;
            }
        }
        __syncthreads();

        const float* __restrict__ wp   = W1t  + ((size_t)(ocb*IC1 + ic0)*9)*64 + tid_oc;
        const float* __restrict__ wscp = Wsct + (size_t)(ocb*IC1 + ic0)*64 + tid_oc;

        for (int ic = 0; ic < 8; ++ic) {
            float w[9];
            #pragma unroll
            for (int k = 0; k < 9; ++k) w[k] = wp[(ic*9 + k)*64];
            const float wsc = wscp[ic*64];
            const float* xb = &Xs[(ic*5 + 2*tid_r)*64 + 28*h];

            #pragma unroll
            for (int ky = 0; ky < 3; ++ky) {
                float xv[32];
                const float4* rp = (const float4*)(xb + ky*64);
                #pragma unroll
                for (int i = 0; i < 8; ++i) *(float4*)&xv[i*4] = rp[i];
                #pragma unroll
                for (int kx = 0; kx < 3; ++kx) {
                    float wv = w[ky*3 + kx];
                    #pragma unroll
                    for (int p = 0; p < 14; ++p)
                        acc[p] = __builtin_fmaf(xv[2*p + kx], wv, acc[p]);
                }
                if (ky == 1) {
                    #pragma unroll
                    for (int p = 0; p < 14; ++p)
                        accid[p] = __builtin_fmaf(xv[2*p + 1], wsc, accid[p]);
                }
            }
        }
    }

    // ---- write S (bf16-bit sign) and identity (fp32), channels-last
    const int oy = ytile*2 + tid_r;
    #pragma unroll
    for (int p = 0; p < 14; ++p) {
        int ox = h*14 + p;
        size_t sidx = (((size_t)n*HWO + oy)*HWO + ox)*OCN + oc0 + tid_oc;
        S[sidx] = bsign_bits(acc[p]);
        I[sidx] = accid[p];
    }
}

// ---------------------------------------------------------------------------
// convB: conv2 (3x3 s1 p1, binary x binary) via MFMA + identity + sign.
// Byte-identical to validated rounds 1-2 (exact integer arithmetic).
// ---------------------------------------------------------------------------
#define SPAD 40
__global__ __launch_bounds__(256, 2) void convB(const unsigned short* __restrict__ S,
                                                const unsigned short* __restrict__ W2t,
                                                const float* __restrict__ I,
                                                float* __restrict__ out) {
    __shared__ unsigned short As[256*SPAD];
    __shared__ unsigned short Bs[64*SPAD];

    const int t    = threadIdx.x;
    const int lane = t & 63;
    const int wave = t >> 6;
    const int px0  = blockIdx.x * 64;

    f32x4_t acc[4][4];
    #pragma unroll
    for (int mi = 0; mi < 4; ++mi)
        #pragma unroll
        for (int ni = 0; ni < 4; ++ni)
            acc[mi][ni] = (f32x4_t)0.f;

    const int b_px  = t >> 2;
    const int b_icg = t & 3;
    const int pxg   = px0 + b_px;
    const int nb    = pxg / PX_PER_IMG;
    const int prb   = pxg % PX_PER_IMG;
    const int oyb   = prb / HWO;
    const int oxb   = prb % HWO;

    for (int ic0 = 0; ic0 < OCN; ic0 += 32) {
        for (int kidx = 0; kidx < 9; ++kidx) {
            const int ky = kidx / 3, kx = kidx % 3;
            __syncthreads();
            #pragma unroll
            for (int i = 0; i < 4; ++i) {
                int uu = t + 256*i;
                int oc = uu >> 2, icgl = uu & 3;
                uint4 v = *(const uint4*)&W2t[(kidx*OCN + oc)*OCN + ic0 + icgl*8];
                *(uint4*)&As[oc*SPAD + icgl*8] = v;
            }
            {
                int sy = oyb + ky - 1, sx = oxb + kx - 1;
                uint4 v = make_uint4(0u, 0u, 0u, 0u);
                if (sy >= 0 && sy < HWO && sx >= 0 && sx < HWO)
                    v = *(const uint4*)&S[((nb*HWO + sy)*HWO + sx)*OCN + ic0 + b_icg*8];
                *(uint4*)&Bs[b_px*SPAD + b_icg*8] = v;
            }
            __syncthreads();
            bf16x8_t a[4], b[4];
            #pragma unroll
            for (int mi = 0; mi < 4; ++mi) {
                int oc = wave*64 + mi*16 + (lane & 15);
                a[mi] = __builtin_bit_cast(bf16x8_t, *(const uint4*)&As[oc*SPAD + (lane >> 4)*8]);
            }
            #pragma unroll
            for (int ni = 0; ni < 4; ++ni) {
                int px = ni*16 + (lane & 15);
                b[ni] = __builtin_bit_cast(bf16x8_t, *(const uint4*)&Bs[px*SPAD + (lane >> 4)*8]);
            }
            #pragma unroll
            for (int mi = 0; mi < 4; ++mi)
                #pragma unroll
                for (int ni = 0; ni < 4; ++ni)
                    acc[mi][ni] = __builtin_amdgcn_mfma_f32_16x16x32_bf16(a[mi], b[ni], acc[mi][ni], 0, 0, 0);
        }
    }

    #pragma unroll
    for (int ni = 0; ni < 4; ++ni) {
        int px = px0 + ni*16 + (lane & 15);
        int n  = px / PX_PER_IMG;
        int pr = px % PX_PER_IMG;
        int oy = pr / HWO, ox = pr % HWO;
        #pragma unroll
        for (int mi = 0; mi < 4; ++mi) {
            int oc = wave*64 + mi*16 + (lane >> 4)*4;
            f32x4_t idv = *(const f32x4_t*)&I[(size_t)px*OCN + oc];
            #pragma unroll
            for (int r = 0; r < 4; ++r) {
                float v = acc[mi][ni][r] + idv[r];
                out[((size_t)(n*OCN + oc + r)*HWO + oy)*HWO + ox] = fsign(v);
            }
        }
    }
}

// ---------------------------------------------------------------------------
// Workspace layout (byte-identical to validated round 2, 79.6 MB):
//  S    : 25,690,112  @ 0
//  I    : 51,380,224  @ 25,690,112
//  W1t  : 1,179,648   @ 77,070,336
//  Wsct : 131,072     @ 78,249,984
//  W2t  : 1,179,648   @ 78,381,056
// ---------------------------------------------------------------------------
extern "C" void kernel_launch(void* const* d_in, const int* in_sizes, int n_in,
                              void* d_out, int out_size, void* d_ws, size_t ws_size,
                              hipStream_t stream) {
    (void)in_sizes; (void)n_in; (void)out_size; (void)ws_size;
    const float* x   = (const float*)d_in[0];
    const float* w1  = (const float*)d_in[1];
    const float* w2  = (const float*)d_in[2];
    const float* wsc = (const float*)d_in[3];
    float* out = (float*)d_out;

    char* ws = (char*)d_ws;
    unsigned short* S    = (unsigned short*)(ws);
    float*          I    = (float*)(ws + 25690112u);
    float*          W1t  = (float*)(ws + 77070336u);
    float*          Wsct = (float*)(ws + 78249984u);
    unsigned short* W2t  = (unsigned short*)(ws + 78381056u);

    hipLaunchKernelGGL(transform_weights, dim3(3584), dim3(256), 0, stream,
                       w1, w2, wsc, W1t, Wsct, W2t);
    hipLaunchKernelGGL(convA, dim3(4, 14, 64), dim3(256), 0, stream,
                       x, W1t, Wsct, S, I);
    hipLaunchKernelGGL(convB, dim3(784), dim3(256), 0, stream,
                       S, W2t, I, out);
}

// Round 6
// 838.287 us; speedup vs baseline: 1.9069x; 1.0687x over previous
//
#include <hip/hip_runtime.h>
#include <cstdint>

// Problem dims
#define N_IMG 64
#define IC1   128
#define HWI   56
#define OCN   256
#define HWO   28
#define PX_PER_IMG (HWO*HWO)          // 784

typedef float  f32x4_t  __attribute__((ext_vector_type(4)));
typedef __bf16 bf16x8_t __attribute__((ext_vector_type(8)));

__device__ __forceinline__ float fsign(float v) {
    return v > 0.f ? 1.f : (v < 0.f ? -1.f : 0.f);
}
__device__ __forceinline__ unsigned short bsign_bits(float v) {
    return v > 0.f ? (unsigned short)0x3F80 : (v < 0.f ? (unsigned short)0xBF80 : (unsigned short)0);
}

// ---------------------------------------------------------------------------
// Weight pre-transform.
//  W1t2 : [ocb2][ic128][k9][oc128] fp32  -- per-(ocb, ic-chunk) slice is LINEAR
//  Wsct2: [ocb2][ic128][oc128]     fp32  -- ditto
//  W2t  : [kidx9][oc256][ic256]    bf16 bits (validated rounds 1-5)
// ---------------------------------------------------------------------------
__global__ void transform_weights(const float* __restrict__ w1,
                                  const float* __restrict__ w2,
                                  const float* __restrict__ wsc,
                                  float* __restrict__ W1t2,
                                  float* __restrict__ Wsct2,
                                  unsigned short* __restrict__ W2t) {
    int idx = blockIdx.x * 256 + threadIdx.x;
    if (idx < 2*128*9*128) {                     // W1t2 (294912)
        int oc128 = idx & 127;
        int rest  = idx >> 7;                    // 0..2303
        int k     = rest % 9;
        int icc   = rest / 9;                    // 0..255
        int ic    = icc & 127;
        int ocb   = icc >> 7;
        int oc_g  = ocb*128 + oc128;
        W1t2[idx] = fsign(w1[(oc_g*IC1 + ic)*9 + k]);
    }
    idx -= 2*128*9*128;
    if (idx >= 0 && idx < 2*128*128) {           // Wsct2 (32768)
        int oc128 = idx & 127;
        int ic    = (idx >> 7) & 127;
        int ocb   = idx >> 14;
        int oc_g  = ocb*128 + oc128;
        Wsct2[idx] = fsign(wsc[oc_g*IC1 + ic]);
    }
    idx -= 2*128*128;
    if (idx >= 0 && idx < 9*256*256) {           // W2t
        int ic = idx & 255; int rest = idx >> 8;
        int oc = rest & 255; int kidx = rest >> 8;
        W2t[idx] = bsign_bits(w2[(oc*OCN + ic)*9 + kidx]);
    }
}

// ---------------------------------------------------------------------------
// convA: conv1 (3x3 s2 p1) + sign -> S; shortcut (1x1 s2) -> I.
// EXACT validated fp32 accumulation order per output (ic 0..127 ascending;
// per ic: ky 0..2 then kx 0..2; shortcut fma at ky==1).
// Round-6 change: 2 oc per thread (2x FMA density), weights staged to LDS by
// flat linear copy so all weight/x reads are ds_read with immediate offsets.
// Block: 256 thr = 64 oc-lanes x {2 out-rows x 2 half-rows}; tile 128 oc x
// 2 rows x 28 cols. Grid (2,14,64). LDS 50 KB -> 3 blocks/CU.
// Live regs ~110 (acc 56 + xv 32 + temps) < 128.
// ---------------------------------------------------------------------------
__global__ __launch_bounds__(256, 2) void convA(const float* __restrict__ x,
                                                const float* __restrict__ W1t2,
                                                const float* __restrict__ Wsct2,
                                                unsigned short* __restrict__ S,
                                                float* __restrict__ I) {
    __shared__ float Xs[8*5*64];     // [ic8][row5][col64], col = ix+1 : 10.0 KB
    __shared__ float Ws[8*9*128];    // [ic8][k9][oc128]               : 36.0 KB
    __shared__ float Wss[8*128];     // [ic8][oc128]                   :  4.0 KB

    const int t      = threadIdx.x;
    const int ocb    = blockIdx.x;        // 2
    const int ytile  = blockIdx.y;        // 14 (2 out rows each)
    const int n      = blockIdx.z;        // 64
    const int tid_oc = t & 63;
    const int u      = t >> 6;            // 0..3
    const int tid_r  = u >> 1;            // out row within tile
    const int h      = u & 1;             // half-row (14 px)

    float acc[2][14], accid[2][14];
    #pragma unroll
    for (int o = 0; o < 2; ++o)
        #pragma unroll
        for (int p = 0; p < 14; ++p) { acc[o][p] = 0.f; accid[o][p] = 0.f; }

    const int s_col = t & 63;
    const int s_icw = (t >> 6) * 2;
    const int s_ix  = s_col - 1;

    for (int chunk = 0; chunk < 16; ++chunk) {
        const int ic0 = chunk * 8;
        __syncthreads();
        // ---- stage Xs: 8 ic x 5 rows x 64 cols, coalesced, guarded zero-pad
        #pragma unroll
        for (int r = 0; r < 5; ++r) {
            int iy = 4*ytile - 1 + r;
            #pragma unroll
            for (int j = 0; j < 2; ++j) {
                int ic = s_icw + j;
                float v = 0.f;
                if ((unsigned)iy < (unsigned)HWI && (unsigned)s_ix < (unsigned)HWI)
                    v = x[((size_t)(n*IC1 + ic0 + ic)*HWI + iy)*HWI + s_ix];
                Xs[(ic*5 + r)*64 + s_col] = v;
            }
        }
        // ---- stage Ws: flat linear copy (2304 float4, 9 per thread)
        {
            const float4* src = (const float4*)(W1t2 + (size_t)(ocb*IC1 + ic0)*9*128);
            #pragma unroll
            for (int i = 0; i < 9; ++i) {
                int li = i*256 + t;
                *(float4*)&Ws[li*4] = src[li];
            }
            const float4* src2 = (const float4*)(Wsct2 + (size_t)(ocb*IC1 + ic0)*128);
            *(float4*)&Wss[t*4] = src2[t];
        }
        __syncthreads();

        for (int ic = 0; ic < 8; ++ic) {
            const float* xb = &Xs[(ic*5 + 2*tid_r)*64 + 28*h];
            const float wsc0 = Wss[ic*128 + tid_oc];
            const float wsc1 = Wss[ic*128 + 64 + tid_oc];

            #pragma unroll
            for (int ky = 0; ky < 3; ++ky) {
                float xv[32];
                const float4* rp = (const float4*)(xb + ky*64);
                #pragma unroll
                for (int i = 0; i < 8; ++i) *(float4*)&xv[i*4] = rp[i];
                #pragma unroll
                for (int kx = 0; kx < 3; ++kx) {
                    const float w0 = Ws[(ic*9 + ky*3 + kx)*128 + tid_oc];
                    const float w1v = Ws[(ic*9 + ky*3 + kx)*128 + 64 + tid_oc];
                    #pragma unroll
                    for (int p = 0; p < 14; ++p)
                        acc[0][p] = __builtin_fmaf(xv[2*p + kx], w0, acc[0][p]);
                    #pragma unroll
                    for (int p = 0; p < 14; ++p)
                        acc[1][p] = __builtin_fmaf(xv[2*p + kx], w1v, acc[1][p]);
                }
                if (ky == 1) {
                    #pragma unroll
                    for (int p = 0; p < 14; ++p)
                        accid[0][p] = __builtin_fmaf(xv[2*p + 1], wsc0, accid[0][p]);
                    #pragma unroll
                    for (int p = 0; p < 14; ++p)
                        accid[1][p] = __builtin_fmaf(xv[2*p + 1], wsc1, accid[1][p]);
                }
            }
        }
    }

    // ---- write S (bf16-bit sign) and identity (fp32), channels-last
    const int oy = ytile*2 + tid_r;
    #pragma unroll
    for (int o = 0; o < 2; ++o) {
        #pragma unroll
        for (int p = 0; p < 14; ++p) {
            int ox = h*14 + p;
            size_t sidx = (((size_t)n*HWO + oy)*HWO + ox)*OCN + ocb*128 + o*64 + tid_oc;
            S[sidx] = bsign_bits(acc[o][p]);
            I[sidx] = accid[o][p];
        }
    }
}

// ---------------------------------------------------------------------------
// convB: conv2 (3x3 s1 p1, binary x binary) via MFMA + identity + sign.
// Byte-identical to validated rounds 1-5 (exact integer arithmetic).
// ---------------------------------------------------------------------------
#define SPAD 40
__global__ __launch_bounds__(256, 2) void convB(const unsigned short* __restrict__ S,
                                                const unsigned short* __restrict__ W2t,
                                                const float* __restrict__ I,
                                                float* __restrict__ out) {
    __shared__ unsigned short As[256*SPAD];
    __shared__ unsigned short Bs[64*SPAD];

    const int t    = threadIdx.x;
    const int lane = t & 63;
    const int wave = t >> 6;
    const int px0  = blockIdx.x * 64;

    f32x4_t acc[4][4];
    #pragma unroll
    for (int mi = 0; mi < 4; ++mi)
        #pragma unroll
        for (int ni = 0; ni < 4; ++ni)
            acc[mi][ni] = (f32x4_t)0.f;

    const int b_px  = t >> 2;
    const int b_icg = t & 3;
    const int pxg   = px0 + b_px;
    const int nb    = pxg / PX_PER_IMG;
    const int prb   = pxg % PX_PER_IMG;
    const int oyb   = prb / HWO;
    const int oxb   = prb % HWO;

    for (int ic0 = 0; ic0 < OCN; ic0 += 32) {
        for (int kidx = 0; kidx < 9; ++kidx) {
            const int ky = kidx / 3, kx = kidx % 3;
            __syncthreads();
            #pragma unroll
            for (int i = 0; i < 4; ++i) {
                int uu = t + 256*i;
                int oc = uu >> 2, icgl = uu & 3;
                uint4 v = *(const uint4*)&W2t[(kidx*OCN + oc)*OCN + ic0 + icgl*8];
                *(uint4*)&As[oc*SPAD + icgl*8] = v;
            }
            {
                int sy = oyb + ky - 1, sx = oxb + kx - 1;
                uint4 v = make_uint4(0u, 0u, 0u, 0u);
                if (sy >= 0 && sy < HWO && sx >= 0 && sx < HWO)
                    v = *(const uint4*)&S[((nb*HWO + sy)*HWO + sx)*OCN + ic0 + b_icg*8];
                *(uint4*)&Bs[b_px*SPAD + b_icg*8] = v;
            }
            __syncthreads();
            bf16x8_t a[4], b[4];
            #pragma unroll
            for (int mi = 0; mi < 4; ++mi) {
                int oc = wave*64 + mi*16 + (lane & 15);
                a[mi] = __builtin_bit_cast(bf16x8_t, *(const uint4*)&As[oc*SPAD + (lane >> 4)*8]);
            }
            #pragma unroll
            for (int ni = 0; ni < 4; ++ni) {
                int px = ni*16 + (lane & 15);
                b[ni] = __builtin_bit_cast(bf16x8_t, *(const uint4*)&Bs[px*SPAD + (lane >> 4)*8]);
            }
            #pragma unroll
            for (int mi = 0; mi < 4; ++mi)
                #pragma unroll
                for (int ni = 0; ni < 4; ++ni)
                    acc[mi][ni] = __builtin_amdgcn_mfma_f32_16x16x32_bf16(a[mi], b[ni], acc[mi][ni], 0, 0, 0);
        }
    }

    #pragma unroll
    for (int ni = 0; ni < 4; ++ni) {
        int px = px0 + ni*16 + (lane & 15);
        int n  = px / PX_PER_IMG;
        int pr = px % PX_PER_IMG;
        int oy = pr / HWO, ox = pr % HWO;
        #pragma unroll
        for (int mi = 0; mi < 4; ++mi) {
            int oc = wave*64 + mi*16 + (lane >> 4)*4;
            f32x4_t idv = *(const f32x4_t*)&I[(size_t)px*OCN + oc];
            #pragma unroll
            for (int r = 0; r < 4; ++r) {
                float v = acc[mi][ni][r] + idv[r];
                out[((size_t)(n*OCN + oc + r)*HWO + oy)*HWO + ox] = fsign(v);
            }
        }
    }
}

// ---------------------------------------------------------------------------
// Workspace layout (byte-identical sizes to validated round 5, 79.6 MB):
//  S    : 25,690,112  @ 0
//  I    : 51,380,224  @ 25,690,112
//  W1t2 : 1,179,648   @ 77,070,336
//  Wsct2: 131,072     @ 78,249,984
//  W2t  : 1,179,648   @ 78,381,056
// ---------------------------------------------------------------------------
extern "C" void kernel_launch(void* const* d_in, const int* in_sizes, int n_in,
                              void* d_out, int out_size, void* d_ws, size_t ws_size,
                              hipStream_t stream) {
    (void)in_sizes; (void)n_in; (void)out_size; (void)ws_size;
    const float* x   = (const float*)d_in[0];
    const float* w1  = (const float*)d_in[1];
    const float* w2  = (const float*)d_in[2];
    const float* wsc = (const float*)d_in[3];
    float* out = (float*)d_out;

    char* ws = (char*)d_ws;
    unsigned short* S     = (unsigned short*)(ws);
    float*          I     = (float*)(ws + 25690112u);
    float*          W1t2  = (float*)(ws + 77070336u);
    float*          Wsct2 = (float*)(ws + 78249984u);
    unsigned short* W2t   = (unsigned short*)(ws + 78381056u);

    hipLaunchKernelGGL(transform_weights, dim3(3584), dim3(256), 0, stream,
                       w1, w2, wsc, W1t2, Wsct2, W2t);
    hipLaunchKernelGGL(convA, dim3(2, 14, 64), dim3(256), 0, stream,
                       x, W1t2, Wsct2, S, I);
    hipLaunchKernelGGL(convB, dim3(784), dim3(256), 0, stream,
                       S, W2t, I, out);
}

// Round 7
// 785.353 us; speedup vs baseline: 2.0355x; 1.0674x over previous
//
#include <hip/hip_runtime.h>
#include <cstdint>

// Problem dims
#define N_IMG 64
#define IC1   128
#define HWI   56
#define OCN   256
#define HWO   28
#define PX_PER_IMG (HWO*HWO)          // 784

typedef float  f32x4_t  __attribute__((ext_vector_type(4)));
typedef __bf16 bf16x8_t __attribute__((ext_vector_type(8)));

__device__ __forceinline__ float fsign(float v) {
    return v > 0.f ? 1.f : (v < 0.f ? -1.f : 0.f);
}
__device__ __forceinline__ unsigned short bsign_bits(float v) {
    return v > 0.f ? (unsigned short)0x3F80 : (v < 0.f ? (unsigned short)0xBF80 : (unsigned short)0);
}

// ---------------------------------------------------------------------------
// Weight pre-transform (unchanged from round 6).
//  W1t2 : [ocb2][ic128][k9][oc128] fp32
//  Wsct2: [ocb2][ic128][oc128]     fp32
//  W2t  : [kidx9][oc256][ic256]    bf16 bits (validated rounds 1-6)
// ---------------------------------------------------------------------------
__global__ void transform_weights(const float* __restrict__ w1,
                                  const float* __restrict__ w2,
                                  const float* __restrict__ wsc,
                                  float* __restrict__ W1t2,
                                  float* __restrict__ Wsct2,
                                  unsigned short* __restrict__ W2t) {
    int idx = blockIdx.x * 256 + threadIdx.x;
    if (idx < 2*128*9*128) {                     // W1t2 (294912)
        int oc128 = idx & 127;
        int rest  = idx >> 7;
        int k     = rest % 9;
        int icc   = rest / 9;
        int ic    = icc & 127;
        int ocb   = icc >> 7;
        int oc_g  = ocb*128 + oc128;
        W1t2[idx] = fsign(w1[(oc_g*IC1 + ic)*9 + k]);
    }
    idx -= 2*128*9*128;
    if (idx >= 0 && idx < 2*128*128) {           // Wsct2 (32768)
        int oc128 = idx & 127;
        int ic    = (idx >> 7) & 127;
        int ocb   = idx >> 14;
        int oc_g  = ocb*128 + oc128;
        Wsct2[idx] = fsign(wsc[oc_g*IC1 + ic]);
    }
    idx -= 2*128*128;
    if (idx >= 0 && idx < 9*256*256) {           // W2t
        int ic = idx & 255; int rest = idx >> 8;
        int oc = rest & 255; int kidx = rest >> 8;
        W2t[idx] = bsign_bits(w2[(oc*OCN + ic)*9 + kidx]);
    }
}

// ---------------------------------------------------------------------------
// convA: conv1 (3x3 s2 p1) + sign -> S; shortcut (1x1 s2) -> I.
// EXACT validated fp32 accumulation order per output (ic 0..127 ascending;
// per ic: ky 0..2 then kx 0..2; shortcut fma after ky==1's kx loop).
// Round-7 change: weights back to GLOBAL (L2-hot, coalesced b32 per lane),
// LDS holds only the 10.2KB x-slab -> 16 waves/CU (VGPR-limited), keeping
// round-6's 2-oc FMA density. Weight loads per (ic,ky) (6 values) to keep
// live set ~105 regs < 128.
// ---------------------------------------------------------------------------
__global__ __launch_bounds__(256, 2) void convA(const float* __restrict__ x,
                                                const float* __restrict__ W1t2,
                                                const float* __restrict__ Wsct2,
                                                unsigned short* __restrict__ S,
                                                float* __restrict__ I) {
    __shared__ float Xs[8*5*64];     // [ic8][row5][col64], col = ix+1 : 10.0 KB

    const int t      = threadIdx.x;
    const int ocb    = blockIdx.x;        // 2
    const int ytile  = blockIdx.y;        // 14 (2 out rows each)
    const int n      = blockIdx.z;        // 64
    const int tid_oc = t & 63;
    const int u      = t >> 6;            // 0..3
    const int tid_r  = u >> 1;            // out row within tile
    const int h      = u & 1;             // half-row (14 px)

    float acc[2][14], accid[2][14];
    #pragma unroll
    for (int o = 0; o < 2; ++o)
        #pragma unroll
        for (int p = 0; p < 14; ++p) { acc[o][p] = 0.f; accid[o][p] = 0.f; }

    const int s_col = t & 63;
    const int s_icw = (t >> 6) * 2;
    const int s_ix  = s_col - 1;

    for (int chunk = 0; chunk < 16; ++chunk) {
        const int ic0 = chunk * 8;
        __syncthreads();
        // ---- stage Xs: 8 ic x 5 rows x 64 cols, coalesced, guarded zero-pad
        #pragma unroll
        for (int r = 0; r < 5; ++r) {
            int iy = 4*ytile - 1 + r;
            #pragma unroll
            for (int j = 0; j < 2; ++j) {
                int ic = s_icw + j;
                float v = 0.f;
                if ((unsigned)iy < (unsigned)HWI && (unsigned)s_ix < (unsigned)HWI)
                    v = x[((size_t)(n*IC1 + ic0 + ic)*HWI + iy)*HWI + s_ix];
                Xs[(ic*5 + r)*64 + s_col] = v;
            }
        }
        __syncthreads();

        for (int ic = 0; ic < 8; ++ic) {
            const float* __restrict__ wp   = W1t2  + ((size_t)(ocb*IC1 + ic0 + ic)*9)*128 + tid_oc;
            const float* __restrict__ wscp = Wsct2 + ((size_t)(ocb*IC1 + ic0 + ic))*128 + tid_oc;
            const float wsc0 = wscp[0];
            const float wsc1 = wscp[64];
            const float* xb = &Xs[(ic*5 + 2*tid_r)*64 + 28*h];

            #pragma unroll
            for (int ky = 0; ky < 3; ++ky) {
                float xv[32];
                const float4* rp = (const float4*)(xb + ky*64);
                #pragma unroll
                for (int i = 0; i < 8; ++i) *(float4*)&xv[i*4] = rp[i];
                // 6 weight loads for this (ic, ky): coalesced, L2-hot
                float w0[3], w1v[3];
                #pragma unroll
                for (int kx = 0; kx < 3; ++kx) {
                    w0[kx]  = wp[(ky*3 + kx)*128];
                    w1v[kx] = wp[(ky*3 + kx)*128 + 64];
                }
                #pragma unroll
                for (int kx = 0; kx < 3; ++kx) {
                    #pragma unroll
                    for (int p = 0; p < 14; ++p)
                        acc[0][p] = __builtin_fmaf(xv[2*p + kx], w0[kx], acc[0][p]);
                    #pragma unroll
                    for (int p = 0; p < 14; ++p)
                        acc[1][p] = __builtin_fmaf(xv[2*p + kx], w1v[kx], acc[1][p]);
                }
                if (ky == 1) {
                    #pragma unroll
                    for (int p = 0; p < 14; ++p)
                        accid[0][p] = __builtin_fmaf(xv[2*p + 1], wsc0, accid[0][p]);
                    #pragma unroll
                    for (int p = 0; p < 14; ++p)
                        accid[1][p] = __builtin_fmaf(xv[2*p + 1], wsc1, accid[1][p]);
                }
            }
        }
    }

    // ---- write S (bf16-bit sign) and identity (fp32), channels-last
    const int oy = ytile*2 + tid_r;
    #pragma unroll
    for (int o = 0; o < 2; ++o) {
        #pragma unroll
        for (int p = 0; p < 14; ++p) {
            int ox = h*14 + p;
            size_t sidx = (((size_t)n*HWO + oy)*HWO + ox)*OCN + ocb*128 + o*64 + tid_oc;
            S[sidx] = bsign_bits(acc[o][p]);
            I[sidx] = accid[o][p];
        }
    }
}

// ---------------------------------------------------------------------------
// convB: conv2 (3x3 s1 p1, binary x binary) via MFMA + identity + sign.
// Byte-identical to validated rounds 1-6 (exact integer arithmetic).
// ---------------------------------------------------------------------------
#define SPAD 40
__global__ __launch_bounds__(256, 2) void convB(const unsigned short* __restrict__ S,
                                                const unsigned short* __restrict__ W2t,
                                                const float* __restrict__ I,
                                                float* __restrict__ out) {
    __shared__ unsigned short As[256*SPAD];
    __shared__ unsigned short Bs[64*SPAD];

    const int t    = threadIdx.x;
    const int lane = t & 63;
    const int wave = t >> 6;
    const int px0  = blockIdx.x * 64;

    f32x4_t acc[4][4];
    #pragma unroll
    for (int mi = 0; mi < 4; ++mi)
        #pragma unroll
        for (int ni = 0; ni < 4; ++ni)
            acc[mi][ni] = (f32x4_t)0.f;

    const int b_px  = t >> 2;
    const int b_icg = t & 3;
    const int pxg   = px0 + b_px;
    const int nb    = pxg / PX_PER_IMG;
    const int prb   = pxg % PX_PER_IMG;
    const int oyb   = prb / HWO;
    const int oxb   = prb % HWO;

    for (int ic0 = 0; ic0 < OCN; ic0 += 32) {
        for (int kidx = 0; kidx < 9; ++kidx) {
            const int ky = kidx / 3, kx = kidx % 3;
            __syncthreads();
            #pragma unroll
            for (int i = 0; i < 4; ++i) {
                int uu = t + 256*i;
                int oc = uu >> 2, icgl = uu & 3;
                uint4 v = *(const uint4*)&W2t[(kidx*OCN + oc)*OCN + ic0 + icgl*8];
                *(uint4*)&As[oc*SPAD + icgl*8] = v;
            }
            {
                int sy = oyb + ky - 1, sx = oxb + kx - 1;
                uint4 v = make_uint4(0u, 0u, 0u, 0u);
                if (sy >= 0 && sy < HWO && sx >= 0 && sx < HWO)
                    v = *(const uint4*)&S[((nb*HWO + sy)*HWO + sx)*OCN + ic0 + b_icg*8];
                *(uint4*)&Bs[b_px*SPAD + b_icg*8] = v;
            }
            __syncthreads();
            bf16x8_t a[4], b[4];
            #pragma unroll
            for (int mi = 0; mi < 4; ++mi) {
                int oc = wave*64 + mi*16 + (lane & 15);
                a[mi] = __builtin_bit_cast(bf16x8_t, *(const uint4*)&As[oc*SPAD + (lane >> 4)*8]);
            }
            #pragma unroll
            for (int ni = 0; ni < 4; ++ni) {
                int px = ni*16 + (lane & 15);
                b[ni] = __builtin_bit_cast(bf16x8_t, *(const uint4*)&Bs[px*SPAD + (lane >> 4)*8]);
            }
            #pragma unroll
            for (int mi = 0; mi < 4; ++mi)
                #pragma unroll
                for (int ni = 0; ni < 4; ++ni)
                    acc[mi][ni] = __builtin_amdgcn_mfma_f32_16x16x32_bf16(a[mi], b[ni], acc[mi][ni], 0, 0, 0);
        }
    }

    #pragma unroll
    for (int ni = 0; ni < 4; ++ni) {
        int px = px0 + ni*16 + (lane & 15);
        int n  = px / PX_PER_IMG;
        int pr = px % PX_PER_IMG;
        int oy = pr / HWO, ox = pr % HWO;
        #pragma unroll
        for (int mi = 0; mi < 4; ++mi) {
            int oc = wave*64 + mi*16 + (lane >> 4)*4;
            f32x4_t idv = *(const f32x4_t*)&I[(size_t)px*OCN + oc];
            #pragma unroll
            for (int r = 0; r < 4; ++r) {
                float v = acc[mi][ni][r] + idv[r];
                out[((size_t)(n*OCN + oc + r)*HWO + oy)*HWO + ox] = fsign(v);
            }
        }
    }
}

// ---------------------------------------------------------------------------
// Workspace layout (validated, 79.6 MB):
//  S    : 25,690,112  @ 0
//  I    : 51,380,224  @ 25,690,112
//  W1t2 : 1,179,648   @ 77,070,336
//  Wsct2: 131,072     @ 78,249,984
//  W2t  : 1,179,648   @ 78,381,056
// ---------------------------------------------------------------------------
extern "C" void kernel_launch(void* const* d_in, const int* in_sizes, int n_in,
                              void* d_out, int out_size, void* d_ws, size_t ws_size,
                              hipStream_t stream) {
    (void)in_sizes; (void)n_in; (void)out_size; (void)ws_size;
    const float* x   = (const float*)d_in[0];
    const float* w1  = (const float*)d_in[1];
    const float* w2  = (const float*)d_in[2];
    const float* wsc = (const float*)d_in[3];
    float* out = (float*)d_out;

    char* ws = (char*)d_ws;
    unsigned short* S     = (unsigned short*)(ws);
    float*          I     = (float*)(ws + 25690112u);
    float*          W1t2  = (float*)(ws + 77070336u);
    float*          Wsct2 = (float*)(ws + 78249984u);
    unsigned short* W2t   = (unsigned short*)(ws + 78381056u);

    hipLaunchKernelGGL(transform_weights, dim3(3584), dim3(256), 0, stream,
                       w1, w2, wsc, W1t2, Wsct2, W2t);
    hipLaunchKernelGGL(convA, dim3(2, 14, 64), dim3(256), 0, stream,
                       x, W1t2, Wsct2, S, I);
    hipLaunchKernelGGL(convB, dim3(784), dim3(256), 0, stream,
                       S, W2t, I, out);
}